// Round 7
// baseline (220.956 us; speedup 1.0000x reference)
//
#include <hip/hip_runtime.h>
#include <math.h>

typedef _Float16 f16;
typedef _Float16 half8 __attribute__((ext_vector_type(8)));
typedef float floatx16 __attribute__((ext_vector_type(16)));

#define HW_     3136
#define NPC     50176.0f
#define PB      3364            // 58*58 padded pixels per image
#define PPLANE  53824           // 16 images * PB (chunks per k2-plane)
#define ASTRIDE (2 * PPLANE * 16)   // bytes between s-steps (k2 += 2) = 1722368

// LDS scalar swizzle (conflict-free both phases)
#define SW(c, px) (((px) + ((c) >> 2) + ((c) & 3) * 8) & 63)

// ---------------------------------------------------------------------------
// setup: fused prep (weight quant+pack) | pad (X2 borders) | pack (x -> X2)
//   blocks [0,784)      : pack
//   blocks [784,1240)   : pad
//   blocks [1240,1384)  : prep
// ---------------------------------------------------------------------------
__global__ __launch_bounds__(256) void setup_kernel(
        const float* __restrict__ x,
        const float* __restrict__ w1, const float* __restrict__ wa1,
        const float* __restrict__ w2, const float* __restrict__ wa2,
        char* __restrict__ X2, f16* __restrict__ W2a, f16* __restrict__ W2b,
        float* __restrict__ stats) {
    const int t = threadIdx.x;
    const int blk = blockIdx.x;
    if (blk < 784) {
        // ---- pack: x fp32 [b][c][hw] -> X2 hi/lo fp16 chunks [k2][b][hp][wp]
        if (blk == 0 && t < 512) stats[t] = 0.f;
        const int b = blk / 49;
        const int p0 = (blk - b * 49) * 64;
        const int px = t & 63;
        const int cq = t >> 6;
        const int p = p0 + px;
        const int h = p / 56;
        const int w = p - h * 56;
        const size_t pp = (size_t)b * PB + (h + 1) * 58 + (w + 1);
        const float* xb = x + (size_t)b * 128 * HW_ + p;
#pragma unroll
        for (int s = 0; s < 4; ++s) {
            const int cg = s * 4 + cq;              // 0..15
            half8 hv, lv;
#pragma unroll
            for (int j = 0; j < 8; ++j) {
                const float v = xb[(size_t)(cg * 8 + j) * HW_];
                const f16 hh = (f16)v;
                hv[j] = hh;
                lv[j] = (f16)(v - (float)hh);
            }
            *(half8*)(X2 + ((size_t)cg * PPLANE + pp) * 16) = hv;
            *(half8*)(X2 + ((size_t)(cg + 16) * PPLANE + pp) * 16) = lv;
        }
    } else if (blk < 1240) {
        // ---- pad: zero border chunks
        const int idx = (blk - 784) * 256 + t;     // 116736 = 32*16*228
        const int k2 = idx / 3648;
        const int r = idx - k2 * 3648;
        const int b = r / 228;
        const int j = r - b * 228;
        int h, w;
        if (j < 58)        { h = 0;  w = j; }
        else if (j < 116)  { h = 57; w = j - 58; }
        else { const int k = j - 116; h = 1 + (k >> 1); w = (k & 1) * 57; }
        const size_t chunk = (size_t)k2 * PPLANE + (size_t)b * PB + h * 58 + w;
        float4 z = {0.f, 0.f, 0.f, 0.f};
        *(float4*)(X2 + chunk * 16) = z;
    } else {
        // ---- prep: w -> integer-valued fp16, chunk (tap*16+k2)*128+oc
        const int idx = (blk - 1240) * 256 + t;    // 0..36863
        const float* w;
        const float* wa;
        f16* o;
        int m;
        if (idx < 18432) { w = w1; wa = wa1; o = W2a; m = idx; }
        else             { w = w2; wa = wa2; o = W2b; m = idx - 18432; }
        const int tap = m >> 11;
        const int r = m & 2047;
        const int k2 = r >> 7;
        const int oc = r & 127;
        const float a = wa[tap];
        const float* src = w + ((size_t)(tap * 128 + oc) * 128 + k2 * 8);
        half8 hv;
#pragma unroll
        for (int j = 0; j < 8; ++j)
            hv[j] = (f16)rintf(fminf(fmaxf(src[j] / a, -4.f), 3.f));
        *(half8*)(o + (size_t)m * 8) = hv;
    }
}

// ---------------------------------------------------------------------------
// conv: barrier-free all-register MFMA split-conv.
// Block 64px x 128oc (784 blocks, fine-grained dynamic balance), 4 waves of
// 32px x 64oc. A: 8-deep register rotation, cross-tap refill. B: full
// period-8 fragment set in registers, loaded once per tap from L2 and
// overwritten in place (steps 8..15) with the next tap's fragments.
// No LDS / no __syncthreads in the main loop.
// ---------------------------------------------------------------------------
__global__ __launch_bounds__(256, 2) void conv_kernel(
        const char* __restrict__ X2, const char* __restrict__ W2,
        const float* __restrict__ wav, const float* __restrict__ pav,
        float* __restrict__ cbuf, float* __restrict__ stats) {
    __shared__ float red[512];
    const int t = threadIdx.x;
    const int lane = t & 63;
    const int wv = t >> 6;
    const int wm = wv & 1, wn = wv >> 1;
    const int tile = (blockIdx.x & 7) * 98 + (blockIdx.x >> 3);  // XCD swizzle
    const int kh = lane >> 5;
    const int ln = lane & 31;

    // A base: this lane's pixel, on its kh k2-plane
    int abase;
    {
        const int gp = tile * 64 + wm * 32 + ln;
        const int b = gp / HW_;
        const int p = gp - b * HW_;
        const int h = p / 56;
        const int w = p - h * 56;
        abase = ((b * PB + (h + 1) * 58 + (w + 1)) + kh * PPLANE) << 4;
    }
    // B per-lane fragment offsets (within a tap's 32 KB W2 slab)
    int bofs[2];
#pragma unroll
    for (int nt = 0; nt < 2; ++nt)
        bofs[nt] = (kh * 128 + wn * 64 + nt * 32 + ln) << 4;

    floatx16 facc[2];
#pragma unroll
    for (int nt = 0; nt < 2; ++nt)
#pragma unroll
        for (int r = 0; r < 16; ++r) facc[nt][r] = 0.f;

    // ---- prologue: tap 0 (di=-1, dj=-1 -> doff=-59) ----
    int aoff = abase + (-59 << 4);
    int aoffn = aoff;
    half8 afr[8];
#pragma unroll
    for (int s0 = 0; s0 < 8; ++s0)
        afr[s0] = *(const half8*)(X2 + aoff + s0 * ASTRIDE);
    half8 bfr[2][8];
#pragma unroll
    for (int kf = 0; kf < 8; ++kf)
#pragma unroll
        for (int nt = 0; nt < 2; ++nt)
            bfr[nt][kf] = *(const half8*)(W2 + bofs[nt] + kf * 4096);

#pragma unroll
    for (int tap = 0; tap < 9; ++tap) {
        const float pak = pav[tap];
        const float s1 = wav[tap] / pak;
        if (tap < 8) {
            const int dn = ((tap + 1) % 3 - 1) * 58 + ((tap + 1) / 3 - 1);
            aoffn = abase + (dn << 4);
        }
        const char* wtn = W2 + (tap + 1) * 32768;

        floatx16 acc[2];
#pragma unroll
        for (int nt = 0; nt < 2; ++nt)
#pragma unroll
            for (int r = 0; r < 16; ++r) acc[nt][r] = 0.f;

#pragma unroll
        for (int s = 0; s < 16; ++s) {
#pragma unroll
            for (int nt = 0; nt < 2; ++nt)
                acc[nt] = __builtin_amdgcn_mfma_f32_32x32x16_f16(
                    afr[s & 7], bfr[nt][s & 7], acc[nt], 0, 0, 0);
            // A refill: within-tap lo-planes for s<8, next tap's hi for s>=8
            if (s < 8) {
                afr[s & 7] = *(const half8*)(X2 + aoff + (s + 8) * ASTRIDE);
            } else if (tap < 8) {
                afr[s & 7] = *(const half8*)(X2 + aoffn + (s - 8) * ASTRIDE);
            }
            // B refill in place right after last use (bfr[.][kf] dead after s=kf+8)
            if (tap < 8 && s >= 8) {
                const int kf = s - 8;
#pragma unroll
                for (int nt = 0; nt < 2; ++nt)
                    bfr[nt][kf] = *(const half8*)(wtn + bofs[nt] + kf * 4096);
            }
        }

        // per-tap 8-bit LSQ quantize of the partial sum, accumulate
#pragma unroll
        for (int nt = 0; nt < 2; ++nt)
#pragma unroll
            for (int r = 0; r < 16; ++r) {
                const float q =
                    rintf(fminf(fmaxf(acc[nt][r] * s1, -128.f), 127.f));
                facc[nt][r] = fmaf(q, pak, facc[nt][r]);
            }
        aoff = aoffn;
    }

    // epilogue: cbuf [gp][oc] fp32  (32x32 C/D: row=(r&3)+8*(r>>2)+4*kh, col=ln)
    const int gpb = tile * 64 + wm * 32;
    const int ocb = wn * 64 + ln;
#pragma unroll
    for (int r = 0; r < 16; ++r) {
        const int row = (r & 3) + 8 * (r >> 2) + 4 * kh;
        float* rp = cbuf + (size_t)(gpb + row) * 128 + ocb;
        rp[0]  = facc[0][r];
        rp[32] = facc[1][r];
    }

    // fused BN stats: per-oc sum/sumsq over this block's 64 px
    float sv[2], qv[2];
#pragma unroll
    for (int nt = 0; nt < 2; ++nt) {
        float s = 0.f, q = 0.f;
#pragma unroll
        for (int r = 0; r < 16; ++r) {
            const float v = facc[nt][r];
            s += v;
            q = fmaf(v, v, q);
        }
        s += __shfl_xor(s, 32, 64);   // combine kh halves (same oc, other px)
        q += __shfl_xor(q, 32, 64);
        sv[nt] = s; qv[nt] = q;
    }
    if (lane < 32) {
#pragma unroll
        for (int nt = 0; nt < 2; ++nt) {
            const int oc = wn * 64 + nt * 32 + lane;
            red[oc * 2 + wm] = sv[nt];
            red[256 + oc * 2 + wm] = qv[nt];
        }
    }
    __syncthreads();
    if (t < 128) {
        atomicAdd(&stats[t],       red[2 * t] + red[2 * t + 1]);
        atomicAdd(&stats[128 + t], red[256 + 2 * t] + red[256 + 2 * t + 1]);
    }
}

// ---------------------------------------------------------------------------
// bn_split: cbuf fp32 [gp][oc] -> bn+relu -> X2 hi/lo packed (conv2 input).
// ---------------------------------------------------------------------------
__global__ __launch_bounds__(256) void bn_split_kernel(
        const float* __restrict__ cbuf, const float* __restrict__ stats,
        const float* __restrict__ g, const float* __restrict__ bb,
        char* __restrict__ X2) {
    __shared__ float xs[8192];
    __shared__ float scs[128], shs[128];
    const int t = threadIdx.x;
    if (t < 128) {
        const float m = stats[t] * (1.f / NPC);
        const float var = stats[128 + t] * (1.f / NPC) - m * m;
        const float inv = 1.f / sqrtf(var + 1e-5f);
        const float sc = g[t] * inv;
        scs[t] = sc;
        shs[t] = bb[t] - m * sc;
    }
    __syncthreads();
    const int blk = blockIdx.x;                  // 784
#pragma unroll
    for (int i = 0; i < 8; ++i) {
        const int idx = i * 256 + t;
        const int px = idx >> 5;
        const int q = idx & 31;
        const float4 v = *(const float4*)&cbuf[(size_t)(blk * 64 + px) * 128 + q * 4];
        const float vv[4] = {v.x, v.y, v.z, v.w};
#pragma unroll
        for (int j = 0; j < 4; ++j) {
            const int c = q * 4 + j;
            xs[c * 64 + SW(c, px)] = fmaxf(fmaf(vv[j], scs[c], shs[c]), 0.f);
        }
    }
    __syncthreads();
    const int b = blk / 49;
    const int p0 = (blk - b * 49) * 64;
    const int px = t & 63;
    const int cq = t >> 6;
    const int p = p0 + px;
    const int h = p / 56;
    const int w = p - h * 56;
    const size_t pp = (size_t)b * PB + (h + 1) * 58 + (w + 1);
#pragma unroll
    for (int s = 0; s < 4; ++s) {
        const int cg = s * 4 + cq;
        half8 hv, lv;
#pragma unroll
        for (int j = 0; j < 8; ++j) {
            const int c = cg * 8 + j;
            const float v = xs[c * 64 + SW(c, px)];
            const f16 hh = (f16)v;
            hv[j] = hh;
            lv[j] = (f16)(v - (float)hh);
        }
        *(half8*)(X2 + ((size_t)cg * PPLANE + pp) * 16) = hv;
        *(half8*)(X2 + ((size_t)(cg + 16) * PPLANE + pp) * 16) = lv;
    }
}

// ---------------------------------------------------------------------------
// final: bn2 + residual add + relu, [gp][oc] -> [b][c][hw] via swizzled LDS
// ---------------------------------------------------------------------------
__global__ __launch_bounds__(256) void final_kernel(
        const float* __restrict__ cbuf, const float* __restrict__ stats,
        const float* __restrict__ g, const float* __restrict__ bb,
        const float* __restrict__ resid, float* __restrict__ out) {
    __shared__ float xs[8192];
    __shared__ float scs[128], shs[128];
    const int t = threadIdx.x;
    if (t < 128) {
        const float m = stats[t] * (1.f / NPC);
        const float var = stats[128 + t] * (1.f / NPC) - m * m;
        const float inv = 1.f / sqrtf(var + 1e-5f);
        const float sc = g[t] * inv;
        scs[t] = sc;
        shs[t] = bb[t] - m * sc;
    }
    __syncthreads();
    const int blk = blockIdx.x;                  // 784
#pragma unroll
    for (int i = 0; i < 8; ++i) {
        const int idx = i * 256 + t;
        const int px = idx >> 5;
        const int q = idx & 31;
        const float4 v = *(const float4*)&cbuf[(size_t)(blk * 64 + px) * 128 + q * 4];
        const float vv[4] = {v.x, v.y, v.z, v.w};
#pragma unroll
        for (int j = 0; j < 4; ++j) {
            const int c = q * 4 + j;
            xs[c * 64 + SW(c, px)] = fmaf(vv[j], scs[c], shs[c]);
        }
    }
    __syncthreads();
    const int b = blk / 49;
    const int p0 = (blk - b * 49) * 64;
    const int lane = t & 63, wq = t >> 6;
#pragma unroll
    for (int i = 0; i < 32; ++i) {
        const int c = i * 4 + wq;
        const float v = xs[c * 64 + SW(c, lane)];
        const size_t gi = (size_t)(b * 128 + c) * HW_ + p0 + lane;
        out[gi] = fmaxf(v + resid[gi], 0.f);
    }
}

// ---------------------------------------------------------------------------
extern "C" void kernel_launch(void* const* d_in, const int* in_sizes, int n_in,
                              void* d_out, int out_size, void* d_ws, size_t ws_size,
                              hipStream_t stream) {
    const float* x   = (const float*)d_in[0];
    const float* w1  = (const float*)d_in[1];
    const float* wa1 = (const float*)d_in[2];
    const float* pa1 = (const float*)d_in[3];
    const float* g1  = (const float*)d_in[4];
    const float* b1  = (const float*)d_in[5];
    const float* w2  = (const float*)d_in[6];
    const float* wa2 = (const float*)d_in[7];
    const float* pa2 = (const float*)d_in[8];
    const float* g2  = (const float*)d_in[9];
    const float* b2  = (const float*)d_in[10];
    float* out = (float*)d_out;

    // ws layout (bytes):
    //   X2    @ 0          : 27,557,888  (32 planes * 53824 chunks * 16 B)
    //   cbuf  @ 27,557,888 : 25,690,112
    //   W2a   @ 53,248,000 :    294,912  (+ tap-9 slack never dereferenced)
    //   W2b   @ 53,542,912 :    294,912
    //   stats @ 53,837,824 :      2,048
    char* ws = (char*)d_ws;
    char*  X2    = ws;
    float* cbuf  = (float*)(ws + 27557888);
    f16*   W2a   = (f16*)(ws + 53248000);
    f16*   W2b   = (f16*)(ws + 53542912);
    float* stats = (float*)(ws + 53837824);
    float* stats1 = stats;
    float* stats2 = stats + 256;

    hipLaunchKernelGGL(setup_kernel, dim3(1384), dim3(256), 0, stream,
                       x, w1, wa1, w2, wa2, X2, W2a, W2b, stats);
    hipLaunchKernelGGL(conv_kernel, dim3(784), dim3(256), 0, stream,
                       X2, (const char*)W2a, wa1, pa1, cbuf, stats1);
    hipLaunchKernelGGL(bn_split_kernel, dim3(784), dim3(256), 0, stream,
                       cbuf, stats1, g1, b1, X2);
    hipLaunchKernelGGL(conv_kernel, dim3(784), dim3(256), 0, stream,
                       X2, (const char*)W2b, wa2, pa2, cbuf, stats2);
    hipLaunchKernelGGL(final_kernel, dim3(784), dim3(256), 0, stream,
                       cbuf, stats2, g2, b2, x, out);
}